// Round 14
// baseline (789.678 us; speedup 1.0000x reference)
//
#include <hip/hip_runtime.h>

#define T_TOK 8192
#define DIM   1024
#define DFF_  4096
#define NE    8
#define MAXT  144

typedef float  f32x4 __attribute__((ext_vector_type(4)));
typedef __bf16 b16x8 __attribute__((ext_vector_type(8)));
typedef unsigned short u16x4 __attribute__((ext_vector_type(4)));
typedef unsigned short u16x8 __attribute__((ext_vector_type(8)));

__device__ __forceinline__ unsigned short f2bf(float f) {
  union { float f; unsigned int u; } v; v.f = f;
  unsigned int r = v.u + 0x7fffu + ((v.u >> 16) & 1u);
  return (unsigned short)(r >> 16);
}

__device__ __forceinline__ void gload_lds16(const void* g, void* l) {
  __builtin_amdgcn_global_load_lds((const __attribute__((address_space(1))) void*)g,
                                   (__attribute__((address_space(3))) void*)l,
                                   16, 0, 0);
}

// r2: explicit vmcnt drain before barrier on the 2-phase schedule.
// r4/r7/r10: coarse counted rings at 16 waves regress; r12: XCD swizzle regresses
//   (L3 temporal reuse already optimal). This round: faithful m201 8-phase port
//   for gemm1 at 8 waves (fat 128-row wave tiles = 25% less LDS traffic, phase-pure
//   MFMA clusters, ONE counted vmcnt per slot). gemm2 stays r9 drain-0 control.
#define DRAIN_VMCNT() asm volatile("s_waitcnt vmcnt(0)" ::: "memory")
#define WAITCNT(n) asm volatile("s_waitcnt vmcnt(" #n ")" ::: "memory")
#define LGKM0() asm volatile("s_waitcnt lgkmcnt(0)" ::: "memory")
#define SBAR() do { asm volatile("" ::: "memory"); __builtin_amdgcn_s_barrier(); \
                    asm volatile("" ::: "memory"); } while (0)

// ---------------- transpose + fp32->bf16 convert ----------------
__device__ __forceinline__ void tcvt_body(const float* __restrict__ src,
                                          unsigned short* __restrict__ dst,
                                          int R, int C, int bx, int by) {
  __shared__ float tile[64 * 64];
  int c0 = bx * 64, r0 = by * 64;
  int t = threadIdx.x;
  const float* s = src + (size_t)r0 * C + c0;
  int rrow = t >> 4, c4r = t & 15;
#pragma unroll
  for (int i = 0; i < 4; i++) {
    int r = rrow + i * 16;
    f32x4 v = *(const f32x4*)(s + (size_t)r * C + c4r * 4);
    int c4s = c4r ^ (r >> 3);
    *(f32x4*)(&tile[r * 64 + c4s * 4]) = v;
  }
  __syncthreads();
  unsigned short* d = dst + (size_t)c0 * R + r0;
  int wr8 = (t & 7) * 8, wcol = t >> 3;
#pragma unroll
  for (int i = 0; i < 2; i++) {
    int cc = wcol + i * 32;
    u16x8 o;
#pragma unroll
    for (int j = 0; j < 8; j++) {
      int r = wr8 + j;
      int c4 = (cc >> 2) ^ (r >> 3);
      o[j] = f2bf(tile[r * 64 + c4 * 4 + (cc & 3)]);
    }
    *(u16x8*)(&d[(size_t)cc * R + wr8]) = o;
  }
}

__global__ __launch_bounds__(256) void transpose_cvt(const float* __restrict__ src,
                                                     unsigned short* __restrict__ dst,
                                                     int R, int C) {
  size_t mat = (size_t)blockIdx.z * R * C;
  tcvt_body(src + mat, dst + mat, R, C, blockIdx.x, blockIdx.y);
}

__global__ __launch_bounds__(256) void transpose_cvt12(const float* __restrict__ W1,
                                                       const float* __restrict__ W2,
                                                       unsigned short* __restrict__ W1T,
                                                       unsigned short* __restrict__ W2T) {
  int z = blockIdx.z;
  size_t mat = (size_t)(z & 7) * DIM * DFF_;
  const float* src = (z < 8 ? W1 : W2) + mat;
  unsigned short* dst = (z < 8 ? W1T : W2T) + mat;
  tcvt_body(src, dst, DIM, DFF_, blockIdx.x, blockIdx.y);
}

// ---------------- router ----------------
__global__ __launch_bounds__(256) void router_k(const float* __restrict__ x,
                                                const float* __restrict__ Wr,
                                                const float* __restrict__ br,
                                                unsigned short* __restrict__ Xbf,
                                                int* __restrict__ top2e,
                                                float* __restrict__ top2w,
                                                int* __restrict__ counts) {
  __shared__ int lcnt[NE];
  if (threadIdx.x < NE) lcnt[threadIdx.x] = 0;
  __syncthreads();
  int wid = threadIdx.x >> 6, lane = threadIdx.x & 63;
  int t = blockIdx.x * 4 + wid;
  const float* xr = x + (size_t)t * DIM;
  unsigned short* xb = Xbf + (size_t)t * DIM;
  float s[NE];
#pragma unroll
  for (int e = 0; e < NE; e++) s[e] = 0.f;
  for (int i = 0; i < DIM / 256; i++) {
    int dd = i * 256 + lane * 4;
    f32x4 xv = *(const f32x4*)(xr + dd);
    u16x4 xb4;
#pragma unroll
    for (int j = 0; j < 4; j++) xb4[j] = f2bf(xv[j]);
    *(u16x4*)(&xb[dd]) = xb4;
#pragma unroll
    for (int j = 0; j < 4; j++) {
      const float* w = Wr + (size_t)(dd + j) * NE;
#pragma unroll
      for (int e = 0; e < NE; e++) s[e] += xv[j] * w[e];
    }
  }
#pragma unroll
  for (int m = 32; m >= 1; m >>= 1) {
#pragma unroll
    for (int e = 0; e < NE; e++) s[e] += __shfl_xor(s[e], m, 64);
  }
  if (lane == 0) {
#pragma unroll
    for (int e = 0; e < NE; e++) s[e] += br[e];
    int e0 = 0;
#pragma unroll
    for (int e = 1; e < NE; e++) if (s[e] > s[e0]) e0 = e;
    int e1 = (e0 == 0) ? 1 : 0;
#pragma unroll
    for (int e = 0; e < NE; e++) if (e != e0 && s[e] > s[e1]) e1 = e;
    float w0 = 1.f / (1.f + expf(s[e1] - s[e0]));
    top2e[2 * t] = e0; top2e[2 * t + 1] = e1;
    top2w[2 * t] = w0; top2w[2 * t + 1] = 1.f - w0;
    atomicAdd(&lcnt[e0], 1);
    atomicAdd(&lcnt[e1], 1);
  }
  __syncthreads();
  if (threadIdx.x < NE) atomicAdd(&counts[threadIdx.x], lcnt[threadIdx.x]);
}

// ---------------- scan + tile map ----------------
__global__ void scan_build(int* __restrict__ ctrl) {
  if (threadIdx.x != 0 || blockIdx.x != 0) return;
  int* counts = ctrl;
  int* offsets = ctrl + 8;
  int* cursors = ctrl + 16;
  int* nt256 = ctrl + 24;
  int* tE256 = ctrl + 32;
  int* tM256 = ctrl + 32 + MAXT;
  int o = 0;
  for (int e = 0; e < NE; e++) { offsets[e] = o; cursors[e] = o; o += counts[e]; }
  int a = 0;
  for (int e = 0; e < NE; e++)
    for (int m0 = 0; m0 < counts[e]; m0 += 256) { tE256[a] = e; tM256[a] = m0; a++; }
  nt256[0] = a;
}

// ---------------- scatter ----------------
__global__ __launch_bounds__(256) void scatter_k(const int* __restrict__ top2e,
                                                 const float* __restrict__ top2w,
                                                 int* __restrict__ cursors,
                                                 int* __restrict__ list_tok,
                                                 float* __restrict__ list_w) {
  __shared__ int lcnt[NE];
  __shared__ int lbase[NE];
  int tid = threadIdx.x;
  if (tid < NE) lcnt[tid] = 0;
  __syncthreads();
  int t = blockIdx.x * 256 + tid;
  int e0 = top2e[2 * t], e1 = top2e[2 * t + 1];
  int r0 = atomicAdd(&lcnt[e0], 1);
  int r1 = atomicAdd(&lcnt[e1], 1);
  __syncthreads();
  if (tid < NE) lbase[tid] = atomicAdd(&cursors[tid], lcnt[tid]);
  __syncthreads();
  int p0 = lbase[e0] + r0, p1 = lbase[e1] + r1;
  list_tok[p0] = t; list_w[p0] = top2w[2 * t];
  list_tok[p1] = t; list_w[p1] = top2w[2 * t + 1];
}

// ---------------- grouped GEMM1 + fused SwiGLU (m201-style 8-phase port) ----------------
// 512 threads (8 waves, 2M x 4N), BM=256 x BN=128 dual, wave tile 128M x 32N-dual.
// Slot = k-half (32k): A[256][32]@0 + B[256][32]@8192 (B1 rows 0-127, B2 128-255),
// 32KB; ring of 4 (128KB). 4 gloads/wave/slot, prefetch depth 2.
// Per slot: P1 {8 ds_read (m0-3 + B1 + B2), 2 gloads(s+2), BAR, lgkm0, 16 MFMA, BAR}
//           P2 {4 ds_read (m4-7), 2 gloads(s+2), vmcnt(4|0), BAR, lgkm0, 16 MFMA, BAR}
// Ledger at P2 wait: outstanding = s+1(4)+s+2(4)=8, oldest 4 = s+1 -> vmcnt(4) exact;
// at s=NS-2 outstanding=4 (only s+1) -> vmcnt(0). Slot s+2 writes ring (s-2)&3,
// whose last read preceded two barriers ago -> overwrite-safe.
__global__ __launch_bounds__(512, 2) void gemm1_k(const unsigned short* __restrict__ Xbf,
                                                  const unsigned short* __restrict__ W1T,
                                                  const unsigned short* __restrict__ W2T,
                                                  const float* __restrict__ b1,
                                                  const float* __restrict__ b2,
                                                  unsigned short* __restrict__ H,
                                                  const int* __restrict__ list_tok,
                                                  const int* __restrict__ ctrl) {
  const int* counts = ctrl; const int* offsets = ctrl + 8;
  const int* ntile = ctrl + 24;
  const int* tileE = ctrl + 32; const int* tileM = ctrl + 32 + MAXT;
  int bt = blockIdx.y;
  if (bt >= ntile[0]) return;
  int e = tileE[bt], m0 = tileM[bt];
  int Me = counts[e], off = offsets[e];
  int n0 = blockIdx.x * 128;

  __shared__ unsigned short lds[4][16384];  // 4 x 32KB slots

  int tid = threadIdx.x, lane = tid & 63, wid = tid >> 6;  // wid 0..7
  int wr = wid >> 2, wc = wid & 3;                         // 2M x 4N; wave 128M x 32N-dual

  // staging: 32 chunks of 1KB per slot (chunk = 16 rows x 32 k); 4 per wave.
  const unsigned short* gsrc[4];
  unsigned ldsoff[4];
  {
    int lr = lane >> 2;                                // row in chunk (0..15)
    int sc = ((lane & 3) ^ ((lane >> 3) & 3)) * 8;     // pre-swizzled k-col
#pragma unroll
    for (int j = 0; j < 4; j++) {
      int c = wid * 4 + j;                             // 0..31
      ldsoff[j] = c * 512;
      if (c < 16) {
        int r = c * 16 + lr;                           // 0..255
        int tok = (m0 + r < Me) ? list_tok[off + m0 + r] : list_tok[off];
        gsrc[j] = Xbf + (size_t)tok * DIM + sc;
      } else if (c < 24) {
        int n = n0 + (c - 16) * 16 + lr;               // B1 rows 0..127
        gsrc[j] = W1T + ((size_t)e * DFF_ + n) * DIM + sc;
      } else {
        int n = n0 + (c - 24) * 16 + lr;               // B2 rows 128..255
        gsrc[j] = W2T + ((size_t)e * DFF_ + n) * DIM + sc;
      }
    }
  }

  // hoisted swizzled ds_read offsets
  unsigned aoffP[2][4], boff[2];
  {
    int colg = lane >> 4;  // 0..3
#pragma unroll
    for (int ph = 0; ph < 2; ph++)
#pragma unroll
      for (int m = 0; m < 4; m++) {
        int row = wr * 128 + (ph * 4 + m) * 16 + (lane & 15);  // 0..255
        aoffP[ph][m] = row * 32 + ((colg ^ ((row >> 1) & 3)) * 8);
      }
#pragma unroll
    for (int n = 0; n < 2; n++) {
      int row = wc * 32 + n * 16 + (lane & 15);        // 0..127 (B1)
      boff[n] = 8192 + row * 32 + ((colg ^ ((row >> 1) & 3)) * 8);
      // B2 = boff + 4096 (swizzle invariant under +128 rows)
    }
  }

  f32x4 acc1[8][2], acc2[8][2];
#pragma unroll
  for (int i = 0; i < 8; i++)
#pragma unroll
    for (int j = 0; j < 2; j++) {
      acc1[i][j] = f32x4{0.f, 0.f, 0.f, 0.f};
      acc2[i][j] = f32x4{0.f, 0.f, 0.f, 0.f};
    }

  const int NS = DIM / 32;  // 32 slots
  // prologue: stage slots 0,1
#pragma unroll
  for (int sp = 0; sp < 2; sp++)
#pragma unroll
    for (int j = 0; j < 4; j++)
      gload_lds16(gsrc[j] + sp * 32, (void*)(&lds[sp][ldsoff[j]]));
  WAITCNT(4);   // slot 0 landed; slot 1 in flight
  SBAR();

  for (int s = 0; s < NS; s++) {
    const unsigned short* sb = &lds[s & 3][0];
    unsigned short* pb = &lds[(s + 2) & 3][0];
    bool more = (s + 2 < NS);
    b16x8 aF[4], bF1[2], bF2[2];
    // ---- P1: m0-3, both B panels ----
#pragma unroll
    for (int m = 0; m < 4; m++) aF[m] = *(const b16x8*)(sb + aoffP[0][m]);
#pragma unroll
    for (int n = 0; n < 2; n++) {
      bF1[n] = *(const b16x8*)(sb + boff[n]);
      bF2[n] = *(const b16x8*)(sb + boff[n] + 4096);
    }
    if (more) {
      gload_lds16(gsrc[0] + (s + 2) * 32, (void*)(pb + ldsoff[0]));
      gload_lds16(gsrc[1] + (s + 2) * 32, (void*)(pb + ldsoff[1]));
    }
    SBAR();
    LGKM0();
    __builtin_amdgcn_s_setprio(1);
#pragma unroll
    for (int m = 0; m < 4; m++)
#pragma unroll
      for (int n = 0; n < 2; n++) {
        acc1[m][n] = __builtin_amdgcn_mfma_f32_16x16x32_bf16(aF[m], bF1[n], acc1[m][n], 0, 0, 0);
        acc2[m][n] = __builtin_amdgcn_mfma_f32_16x16x32_bf16(aF[m], bF2[n], acc2[m][n], 0, 0, 0);
      }
    __builtin_amdgcn_s_setprio(0);
    SBAR();
    // ---- P2: m4-7 (bF still live) ----
#pragma unroll
    for (int m = 0; m < 4; m++) aF[m] = *(const b16x8*)(sb + aoffP[1][m]);
    if (more) {
      gload_lds16(gsrc[2] + (s + 2) * 32, (void*)(pb + ldsoff[2]));
      gload_lds16(gsrc[3] + (s + 2) * 32, (void*)(pb + ldsoff[3]));
    }
    if (s < NS - 2) { WAITCNT(4); }        // slot s+1 landed; s+2 in flight
    else if (s == NS - 2) { WAITCNT(0); }  // last slot's loads: full drain
    SBAR();
    LGKM0();
    __builtin_amdgcn_s_setprio(1);
#pragma unroll
    for (int m = 0; m < 4; m++)
#pragma unroll
      for (int n = 0; n < 2; n++) {
        acc1[4 + m][n] = __builtin_amdgcn_mfma_f32_16x16x32_bf16(aF[m], bF1[n], acc1[4 + m][n], 0, 0, 0);
        acc2[4 + m][n] = __builtin_amdgcn_mfma_f32_16x16x32_bf16(aF[m], bF2[n], acc2[4 + m][n], 0, 0, 0);
      }
    __builtin_amdgcn_s_setprio(0);
    SBAR();
  }

#pragma unroll
  for (int n = 0; n < 2; n++) {
    int col = n0 + wc * 32 + n * 16 + (lane & 15);
    float bb1 = b1[e * DFF_ + col], bb2 = b2[e * DFF_ + col];
#pragma unroll
    for (int m = 0; m < 8; m++) {
      int rbase = wr * 128 + m * 16 + (lane >> 4) * 4;
#pragma unroll
      for (int r = 0; r < 4; r++) {
        int rr = rbase + r;
        if (m0 + rr < Me) {
          float c1 = acc1[m][n][r] + bb1;
          float c2 = acc2[m][n][r] + bb2;
          float h = c1 * c2 / (1.f + __expf(-c1));  // silu(c1)*c2
          H[(size_t)(off + m0 + rr) * DFF_ + col] = f2bf(h);
        }
      }
    }
  }
}

// ---------------- grouped GEMM2 (r9 CONTROL): y[token] += w * (H @ W3^T + b3) ----------------
__global__ __launch_bounds__(1024, 4) void gemm2_k(const unsigned short* __restrict__ H,
                                                   const unsigned short* __restrict__ W3T,
                                                   const float* __restrict__ b3,
                                                   const int* __restrict__ list_tok,
                                                   const float* __restrict__ list_w,
                                                   float* __restrict__ y,
                                                   const int* __restrict__ ctrl) {
  const int* counts = ctrl; const int* offsets = ctrl + 8;
  const int* ntile = ctrl + 24;
  const int* tileE = ctrl + 32; const int* tileM = ctrl + 32 + MAXT;
  int bt = blockIdx.y;
  if (bt >= ntile[0]) return;
  int e = tileE[bt], m0 = tileM[bt];
  int Me = counts[e], off = offsets[e];
  int n0 = blockIdx.x * 256;

  __shared__ unsigned short lds[2][32768];

  int tid = threadIdx.x, lane = tid & 63, wid = tid >> 6;
  int wr = wid >> 2, wc = wid & 3;

  const unsigned short* gsrc[4];
  unsigned ldsoff[4];
  {
    int lr = lane >> 3;
    int sc = ((lane & 7) ^ (lane >> 3)) * 8;
#pragma unroll
    for (int j = 0; j < 4; j++) {
      int c = wid * 4 + j;
      ldsoff[j] = c * 512;
      if (c < 32) {
        int r = c * 8 + lr;
        int pos = (m0 + r < Me) ? (off + m0 + r) : off;
        gsrc[j] = H + (size_t)pos * DFF_ + sc;
      } else {
        int n = n0 + (c - 32) * 8 + lr;
        gsrc[j] = W3T + ((size_t)e * DIM + n) * DFF_ + sc;
      }
    }
  }

  unsigned aoff[2][4], boff[2][4];
  {
    int colg = lane >> 4;
#pragma unroll
    for (int kk = 0; kk < 2; kk++) {
#pragma unroll
      for (int m = 0; m < 4; m++) {
        int row = wr * 64 + m * 16 + (lane & 15);
        aoff[kk][m] = row * 64 + (((kk * 4 + colg) ^ (row & 7)) * 8);
      }
#pragma unroll
      for (int n = 0; n < 4; n++) {
        int row = wc * 64 + n * 16 + (lane & 15);
        boff[kk][n] = 16384 + row * 64 + (((kk * 4 + colg) ^ (row & 7)) * 8);
      }
    }
  }

  f32x4 acc[4][4];
#pragma unroll
  for (int i = 0; i < 4; i++)
#pragma unroll
    for (int j = 0; j < 4; j++) acc[i][j] = f32x4{0.f, 0.f, 0.f, 0.f};

  auto compute = [&](const unsigned short* base) {
#pragma unroll
    for (int kk = 0; kk < 2; kk++) {
      b16x8 aF[4], bF[4];
#pragma unroll
      for (int m = 0; m < 4; m++) aF[m] = *(const b16x8*)(base + aoff[kk][m]);
#pragma unroll
      for (int n = 0; n < 4; n++) bF[n] = *(const b16x8*)(base + boff[kk][n]);
#pragma unroll
      for (int m = 0; m < 4; m++)
#pragma unroll
        for (int n = 0; n < 4; n++)
          acc[m][n] = __builtin_amdgcn_mfma_f32_16x16x32_bf16(aF[m], bF[n], acc[m][n], 0, 0, 0);
    }
  };

#pragma unroll
  for (int j = 0; j < 4; j++) gload_lds16(gsrc[j], (void*)(&lds[0][ldsoff[j]]));
  DRAIN_VMCNT();
  __syncthreads();

  int cur = 0;
  const int NK = DFF_ / 64;
  for (int kt = 0; kt < NK; kt++) {
    if (kt + 1 < NK) {
#pragma unroll
      for (int j = 0; j < 4; j++)
        gload_lds16(gsrc[j] + (kt + 1) * 64, (void*)(&lds[cur ^ 1][ldsoff[j]]));
    }
    compute(&lds[cur][0]);
    DRAIN_VMCNT();
    __syncthreads();
    cur ^= 1;
  }

#pragma unroll
  for (int n = 0; n < 4; n++) {
    int col = n0 + wc * 64 + n * 16 + (lane & 15);
    float bb3 = b3[e * DIM + col];
#pragma unroll
    for (int m = 0; m < 4; m++) {
      int rbase = wr * 64 + m * 16 + (lane >> 4) * 4;
#pragma unroll
      for (int r = 0; r < 4; r++) {
        int rr = rbase + r;
        if (m0 + rr < Me) {
          int pos = off + m0 + rr;
          float v = list_w[pos] * (acc[m][n][r] + bb3);
          atomicAdd(&y[(size_t)list_tok[pos] * DIM + col], v);
        }
      }
    }
  }
}

extern "C" void kernel_launch(void* const* d_in, const int* in_sizes, int n_in,
                              void* d_out, int out_size, void* d_ws, size_t ws_size,
                              hipStream_t stream) {
  (void)in_sizes; (void)n_in; (void)ws_size;
  const float* x  = (const float*)d_in[0];
  const float* Wr = (const float*)d_in[1];
  const float* br = (const float*)d_in[2];
  const float* W1 = (const float*)d_in[3];
  const float* b1 = (const float*)d_in[4];
  const float* W2 = (const float*)d_in[5];
  const float* b2 = (const float*)d_in[6];
  const float* W3 = (const float*)d_in[7];
  const float* b3 = (const float*)d_in[8];
  float* y = (float*)d_out;
  char* ws = (char*)d_ws;

  const size_t matB = (size_t)NE * DFF_ * DIM * 2;
  size_t oW1T = 0;
  size_t oW2T = oW1T + matB;
  size_t oXbf = oW2T + matB;
  size_t oH   = oXbf + (size_t)T_TOK * DIM * 2;
  size_t oT2e = oH + (size_t)2 * T_TOK * DFF_ * 2;
  size_t oT2w = oT2e + (size_t)2 * T_TOK * 4;
  size_t oLtk = oT2w + (size_t)2 * T_TOK * 4;
  size_t oLw  = oLtk + (size_t)2 * T_TOK * 4;
  size_t oCtl = oLw + (size_t)2 * T_TOK * 4;

  unsigned short* W1T = (unsigned short*)(ws + oW1T);
  unsigned short* W2T = (unsigned short*)(ws + oW2T);
  unsigned short* W3T = (unsigned short*)(ws + oW1T);  // reuse after gemm1
  unsigned short* Xbf = (unsigned short*)(ws + oXbf);
  unsigned short* Hb  = (unsigned short*)(ws + oH);
  int*   top2e = (int*)(ws + oT2e);
  float* top2w = (float*)(ws + oT2w);
  int*   ltok  = (int*)(ws + oLtk);
  float* lw    = (float*)(ws + oLw);
  int*   ctrl  = (int*)(ws + oCtl);

  hipMemsetAsync(y, 0, (size_t)out_size * 4, stream);
  hipMemsetAsync(ctrl, 0, (32 + 2 * MAXT) * 4, stream);

  transpose_cvt12<<<dim3(DFF_ / 64, DIM / 64, 2 * NE), 256, 0, stream>>>(W1, W2, W1T, W2T);
  router_k<<<dim3(T_TOK / 4), 256, 0, stream>>>(x, Wr, br, Xbf, top2e, top2w, ctrl);
  scan_build<<<dim3(1), 64, 0, stream>>>(ctrl);
  scatter_k<<<dim3(T_TOK / 256), 256, 0, stream>>>(top2e, top2w, ctrl + 16, ltok, lw);
  gemm1_k<<<dim3(DFF_ / 128, 71), 512, 0, stream>>>(Xbf, W1T, W2T, b1, b2, Hb, ltok, ctrl);
  transpose_cvt<<<dim3(DIM / 64, DFF_ / 64, NE), 256, 0, stream>>>(W3, W3T, DFF_, DIM);
  gemm2_k<<<dim3(DIM / 256, 71), 1024, 0, stream>>>(Hb, W3T, b3, ltok, lw, y, ctrl);
}

// Round 15
// 711.287 us; speedup vs baseline: 1.1102x; 1.1102x over previous
//
#include <hip/hip_runtime.h>

#define T_TOK 8192
#define DIM   1024
#define DFF_  4096
#define NE    8
#define MAXT  144

typedef float  f32x4 __attribute__((ext_vector_type(4)));
typedef __bf16 b16x8 __attribute__((ext_vector_type(8)));
typedef unsigned short u16x4 __attribute__((ext_vector_type(4)));
typedef unsigned short u16x8 __attribute__((ext_vector_type(8)));

__device__ __forceinline__ unsigned short f2bf(float f) {
  union { float f; unsigned int u; } v; v.f = f;
  unsigned int r = v.u + 0x7fffu + ((v.u >> 16) & 1u);
  return (unsigned short)(r >> 16);
}

__device__ __forceinline__ void gload_lds16(const void* g, void* l) {
  __builtin_amdgcn_global_load_lds((const __attribute__((address_space(1))) void*)g,
                                   (__attribute__((address_space(3))) void*)l,
                                   16, 0, 0);
}

// FINAL LOCKED STATE. Session lessons:
// r2: __syncthreads alone does not drain global_load_lds -> explicit vmcnt(0).
// r3: XOR k-swizzle killed 1e8 bank-conflict stalls (16-way -> 2-way free).
// r8: at fixed 16 waves/CU, wins come from MFMA per drain-barrier:
//     1024 thr / BK=64 / 32 MFMA/wave/barrier = 45% MfmaUtil (~965 TF).
// r4/r7/r10/r13-14: counted-vmcnt / 8-phase schedules regressed 4x at this
//     tile size in plain HIP (barrier-frequency or occupancy always pays more
//     than latency-hiding gains). r11: K-split regressed (atomics+reuse).
// r12: XCD swizzle regressed (FETCH 250->589MB; natural dispatch already has
//     global L3 temporal reuse of the L3-fit weight set).
#define DRAIN_VMCNT() asm volatile("s_waitcnt vmcnt(0)" ::: "memory")

// ---------------- transpose + fp32->bf16 convert: src [R][C] -> dst [C][R] ----------------
// XOR-swizzled LDS (conflict-free both phases), float4 loads, 16B u16x8 stores.
__device__ __forceinline__ void tcvt_body(const float* __restrict__ src,
                                          unsigned short* __restrict__ dst,
                                          int R, int C, int bx, int by) {
  __shared__ float tile[64 * 64];
  int c0 = bx * 64, r0 = by * 64;
  int t = threadIdx.x;
  const float* s = src + (size_t)r0 * C + c0;
  int rrow = t >> 4, c4r = t & 15;
#pragma unroll
  for (int i = 0; i < 4; i++) {
    int r = rrow + i * 16;
    f32x4 v = *(const f32x4*)(s + (size_t)r * C + c4r * 4);
    int c4s = c4r ^ (r >> 3);
    *(f32x4*)(&tile[r * 64 + c4s * 4]) = v;
  }
  __syncthreads();
  unsigned short* d = dst + (size_t)c0 * R + r0;
  int wr8 = (t & 7) * 8, wcol = t >> 3;
#pragma unroll
  for (int i = 0; i < 2; i++) {
    int cc = wcol + i * 32;
    u16x8 o;
#pragma unroll
    for (int j = 0; j < 8; j++) {
      int r = wr8 + j;
      int c4 = (cc >> 2) ^ (r >> 3);
      o[j] = f2bf(tile[r * 64 + c4 * 4 + (cc & 3)]);
    }
    *(u16x8*)(&d[(size_t)cc * R + wr8]) = o;
  }
}

__global__ __launch_bounds__(256) void transpose_cvt(const float* __restrict__ src,
                                                     unsigned short* __restrict__ dst,
                                                     int R, int C) {
  size_t mat = (size_t)blockIdx.z * R * C;
  tcvt_body(src + mat, dst + mat, R, C, blockIdx.x, blockIdx.y);
}

__global__ __launch_bounds__(256) void transpose_cvt12(const float* __restrict__ W1,
                                                       const float* __restrict__ W2,
                                                       unsigned short* __restrict__ W1T,
                                                       unsigned short* __restrict__ W2T) {
  int z = blockIdx.z;
  size_t mat = (size_t)(z & 7) * DIM * DFF_;
  const float* src = (z < 8 ? W1 : W2) + mat;
  unsigned short* dst = (z < 8 ? W1T : W2T) + mat;
  tcvt_body(src, dst, DIM, DFF_, blockIdx.x, blockIdx.y);
}

// ---------------- router: logits (fp32 exact), top-2, softmax weights, bf16 x copy,
// fused per-block expert counting; float4 x loads ----------------
__global__ __launch_bounds__(256) void router_k(const float* __restrict__ x,
                                                const float* __restrict__ Wr,
                                                const float* __restrict__ br,
                                                unsigned short* __restrict__ Xbf,
                                                int* __restrict__ top2e,
                                                float* __restrict__ top2w,
                                                int* __restrict__ counts) {
  __shared__ int lcnt[NE];
  if (threadIdx.x < NE) lcnt[threadIdx.x] = 0;
  __syncthreads();
  int wid = threadIdx.x >> 6, lane = threadIdx.x & 63;
  int t = blockIdx.x * 4 + wid;
  const float* xr = x + (size_t)t * DIM;
  unsigned short* xb = Xbf + (size_t)t * DIM;
  float s[NE];
#pragma unroll
  for (int e = 0; e < NE; e++) s[e] = 0.f;
  for (int i = 0; i < DIM / 256; i++) {
    int dd = i * 256 + lane * 4;
    f32x4 xv = *(const f32x4*)(xr + dd);
    u16x4 xb4;
#pragma unroll
    for (int j = 0; j < 4; j++) xb4[j] = f2bf(xv[j]);
    *(u16x4*)(&xb[dd]) = xb4;
#pragma unroll
    for (int j = 0; j < 4; j++) {
      const float* w = Wr + (size_t)(dd + j) * NE;
#pragma unroll
      for (int e = 0; e < NE; e++) s[e] += xv[j] * w[e];
    }
  }
#pragma unroll
  for (int m = 32; m >= 1; m >>= 1) {
#pragma unroll
    for (int e = 0; e < NE; e++) s[e] += __shfl_xor(s[e], m, 64);
  }
  if (lane == 0) {
#pragma unroll
    for (int e = 0; e < NE; e++) s[e] += br[e];
    int e0 = 0;
#pragma unroll
    for (int e = 1; e < NE; e++) if (s[e] > s[e0]) e0 = e;
    int e1 = (e0 == 0) ? 1 : 0;
#pragma unroll
    for (int e = 0; e < NE; e++) if (e != e0 && s[e] > s[e1]) e1 = e;
    float w0 = 1.f / (1.f + expf(s[e1] - s[e0]));  // softmax over (p0,p1), p0>=p1
    top2e[2 * t] = e0; top2e[2 * t + 1] = e1;
    top2w[2 * t] = w0; top2w[2 * t + 1] = 1.f - w0;
    atomicAdd(&lcnt[e0], 1);
    atomicAdd(&lcnt[e1], 1);
  }
  __syncthreads();
  if (threadIdx.x < NE) atomicAdd(&counts[threadIdx.x], lcnt[threadIdx.x]);
}

// ---------------- scan + grouped-GEMM tile map (256-row granularity) ----------------
__global__ void scan_build(int* __restrict__ ctrl) {
  if (threadIdx.x != 0 || blockIdx.x != 0) return;
  int* counts = ctrl;              // [8]
  int* offsets = ctrl + 8;         // [8]
  int* cursors = ctrl + 16;        // [8]
  int* nt256 = ctrl + 24;          // [1]
  int* tE256 = ctrl + 32;                 // [MAXT]
  int* tM256 = ctrl + 32 + MAXT;          // [MAXT]
  int o = 0;
  for (int e = 0; e < NE; e++) { offsets[e] = o; cursors[e] = o; o += counts[e]; }
  int a = 0;
  for (int e = 0; e < NE; e++)
    for (int m0 = 0; m0 < counts[e]; m0 += 256) { tE256[a] = e; tM256[a] = m0; a++; }
  nt256[0] = a;   // <= 71
}

// ---------------- scatter tokens into per-expert lists (block-local ranks) ----------------
__global__ __launch_bounds__(256) void scatter_k(const int* __restrict__ top2e,
                                                 const float* __restrict__ top2w,
                                                 int* __restrict__ cursors,
                                                 int* __restrict__ list_tok,
                                                 float* __restrict__ list_w) {
  __shared__ int lcnt[NE];
  __shared__ int lbase[NE];
  int tid = threadIdx.x;
  if (tid < NE) lcnt[tid] = 0;
  __syncthreads();
  int t = blockIdx.x * 256 + tid;
  int e0 = top2e[2 * t], e1 = top2e[2 * t + 1];
  int r0 = atomicAdd(&lcnt[e0], 1);
  int r1 = atomicAdd(&lcnt[e1], 1);
  __syncthreads();
  if (tid < NE) lbase[tid] = atomicAdd(&cursors[tid], lcnt[tid]);
  __syncthreads();
  int p0 = lbase[e0] + r0, p1 = lbase[e1] + r1;
  list_tok[p0] = t; list_w[p0] = top2w[2 * t];
  list_tok[p1] = t; list_w[p1] = top2w[2 * t + 1];
}

// ---------------- grouped GEMM1 + fused SwiGLU: H = silu(X@W1+b1)*(X@W2+b2) ----------------
// LOCKED r8/r9 geometry (296us, MfmaUtil 45%, FETCH ~250MB):
// 1024 threads (16 waves, 4Mx4N), BM=256 x BN=128 dual, BK=64, 2-phase drain-0 dbuf,
// 32 dual-MFMA/wave/barrier, XOR k-swizzle g(row)=row&7, LDS 2x64KB.
__global__ __launch_bounds__(1024, 4) void gemm1_k(const unsigned short* __restrict__ Xbf,
                                                   const unsigned short* __restrict__ W1T,
                                                   const unsigned short* __restrict__ W2T,
                                                   const float* __restrict__ b1,
                                                   const float* __restrict__ b2,
                                                   unsigned short* __restrict__ H,
                                                   const int* __restrict__ list_tok,
                                                   const int* __restrict__ ctrl) {
  const int* counts = ctrl; const int* offsets = ctrl + 8;
  const int* ntile = ctrl + 24;
  const int* tileE = ctrl + 32; const int* tileM = ctrl + 32 + MAXT;
  int bt = blockIdx.y;
  if (bt >= ntile[0]) return;
  int e = tileE[bt], m0 = tileM[bt];
  int Me = counts[e], off = offsets[e];
  int n0 = blockIdx.x * 128;

  // slot (ushort elems): A[256][64] @0 (16384), B1[128][64] @16384 (8192), B2 @24576 (8192)
  __shared__ unsigned short lds[2][32768];  // 2 x 64KB = 128KB

  int tid = threadIdx.x, lane = tid & 63, wid = tid >> 6;  // wid 0..15
  int wr = wid >> 2, wc = wid & 3;                         // 4M x 4N, wave = 64 x 32 dual

  const unsigned short* gsrc[4];
  unsigned ldsoff[4];
  {
    int lr = lane >> 3;                            // row within chunk (0..7)
    int sc = ((lane & 7) ^ (lane >> 3)) * 8;       // swizzled k-col (elements)
#pragma unroll
    for (int j = 0; j < 4; j++) {
      int c = wid * 4 + j;                         // 0..63
      ldsoff[j] = c * 512;
      if (c < 32) {
        int r = c * 8 + lr;                        // 0..255
        int tok = (m0 + r < Me) ? list_tok[off + m0 + r] : list_tok[off];
        gsrc[j] = Xbf + (size_t)tok * DIM + sc;
      } else if (c < 48) {
        int n = n0 + (c - 32) * 8 + lr;            // 0..127 within panel
        gsrc[j] = W1T + ((size_t)e * DFF_ + n) * DIM + sc;
      } else {
        int n = n0 + (c - 48) * 8 + lr;
        gsrc[j] = W2T + ((size_t)e * DFF_ + n) * DIM + sc;
      }
    }
  }

  unsigned aoff[2][4], boff[2][2];
  {
    int colg = lane >> 4;  // 0..3
#pragma unroll
    for (int kk = 0; kk < 2; kk++) {
#pragma unroll
      for (int m = 0; m < 4; m++) {
        int row = wr * 64 + m * 16 + (lane & 15);  // 0..255
        aoff[kk][m] = row * 64 + (((kk * 4 + colg) ^ (row & 7)) * 8);
      }
#pragma unroll
      for (int n = 0; n < 2; n++) {
        int row = wc * 32 + n * 16 + (lane & 15);  // 0..127
        boff[kk][n] = 16384 + row * 64 + (((kk * 4 + colg) ^ (row & 7)) * 8);
      }
    }
  }

  f32x4 acc1[4][2], acc2[4][2];
#pragma unroll
  for (int i = 0; i < 4; i++)
#pragma unroll
    for (int j = 0; j < 2; j++) {
      acc1[i][j] = f32x4{0.f, 0.f, 0.f, 0.f};
      acc2[i][j] = f32x4{0.f, 0.f, 0.f, 0.f};
    }

  auto compute = [&](const unsigned short* base) {
#pragma unroll
    for (int kk = 0; kk < 2; kk++) {
      b16x8 aF[4], bF1[2], bF2[2];
#pragma unroll
      for (int m = 0; m < 4; m++) aF[m] = *(const b16x8*)(base + aoff[kk][m]);
#pragma unroll
      for (int n = 0; n < 2; n++) {
        bF1[n] = *(const b16x8*)(base + boff[kk][n]);
        bF2[n] = *(const b16x8*)(base + boff[kk][n] + 8192);
      }
#pragma unroll
      for (int m = 0; m < 4; m++)
#pragma unroll
        for (int n = 0; n < 2; n++) {
          acc1[m][n] = __builtin_amdgcn_mfma_f32_16x16x32_bf16(aF[m], bF1[n], acc1[m][n], 0, 0, 0);
          acc2[m][n] = __builtin_amdgcn_mfma_f32_16x16x32_bf16(aF[m], bF2[n], acc2[m][n], 0, 0, 0);
        }
    }
  };

#pragma unroll
  for (int j = 0; j < 4; j++) gload_lds16(gsrc[j], (void*)(&lds[0][ldsoff[j]]));
  DRAIN_VMCNT();
  __syncthreads();

  int cur = 0;
  const int NK = DIM / 64;  // 16
  for (int kt = 0; kt < NK; kt++) {
    if (kt + 1 < NK) {
#pragma unroll
      for (int j = 0; j < 4; j++)
        gload_lds16(gsrc[j] + (kt + 1) * 64, (void*)(&lds[cur ^ 1][ldsoff[j]]));
    }
    compute(&lds[cur][0]);
    DRAIN_VMCNT();
    __syncthreads();
    cur ^= 1;
  }

#pragma unroll
  for (int n = 0; n < 2; n++) {
    int col = n0 + wc * 32 + n * 16 + (lane & 15);
    float bb1 = b1[e * DFF_ + col], bb2 = b2[e * DFF_ + col];
#pragma unroll
    for (int m = 0; m < 4; m++) {
      int rbase = wr * 64 + m * 16 + (lane >> 4) * 4;
#pragma unroll
      for (int r = 0; r < 4; r++) {
        int rr = rbase + r;
        if (m0 + rr < Me) {
          float c1 = acc1[m][n][r] + bb1;
          float c2 = acc2[m][n][r] + bb2;
          float h = c1 * c2 / (1.f + __expf(-c1));  // silu(c1)*c2
          H[(size_t)(off + m0 + rr) * DFF_ + col] = f2bf(h);
        }
      }
    }
  }
}

// ---------------- grouped GEMM2: y[token] += w * (H @ W3^T + b3) ----------------
// LOCKED r9 geometry, unswizzled, unsplit: 1024 threads (16 waves, 4Mx4N),
// BM=256 x BN=256, BK=64, 2-phase drain-0 dbuf, 32 MFMA/wave/barrier,
// XOR k-swizzle, LDS 2x64KB.
__global__ __launch_bounds__(1024, 4) void gemm2_k(const unsigned short* __restrict__ H,
                                                   const unsigned short* __restrict__ W3T,
                                                   const float* __restrict__ b3,
                                                   const int* __restrict__ list_tok,
                                                   const float* __restrict__ list_w,
                                                   float* __restrict__ y,
                                                   const int* __restrict__ ctrl) {
  const int* counts = ctrl; const int* offsets = ctrl + 8;
  const int* ntile = ctrl + 24;
  const int* tileE = ctrl + 32; const int* tileM = ctrl + 32 + MAXT;
  int bt = blockIdx.y;
  if (bt >= ntile[0]) return;
  int e = tileE[bt], m0 = tileM[bt];
  int Me = counts[e], off = offsets[e];
  int n0 = blockIdx.x * 256;

  __shared__ unsigned short lds[2][32768];  // A[256][64] | B[256][64], 2 x 64KB

  int tid = threadIdx.x, lane = tid & 63, wid = tid >> 6;
  int wr = wid >> 2, wc = wid & 3;

  const unsigned short* gsrc[4];
  unsigned ldsoff[4];
  {
    int lr = lane >> 3;
    int sc = ((lane & 7) ^ (lane >> 3)) * 8;
#pragma unroll
    for (int j = 0; j < 4; j++) {
      int c = wid * 4 + j;
      ldsoff[j] = c * 512;
      if (c < 32) {
        int r = c * 8 + lr;
        int pos = (m0 + r < Me) ? (off + m0 + r) : off;
        gsrc[j] = H + (size_t)pos * DFF_ + sc;
      } else {
        int n = n0 + (c - 32) * 8 + lr;
        gsrc[j] = W3T + ((size_t)e * DIM + n) * DFF_ + sc;
      }
    }
  }

  unsigned aoff[2][4], boff[2][4];
  {
    int colg = lane >> 4;
#pragma unroll
    for (int kk = 0; kk < 2; kk++) {
#pragma unroll
      for (int m = 0; m < 4; m++) {
        int row = wr * 64 + m * 16 + (lane & 15);
        aoff[kk][m] = row * 64 + (((kk * 4 + colg) ^ (row & 7)) * 8);
      }
#pragma unroll
      for (int n = 0; n < 4; n++) {
        int row = wc * 64 + n * 16 + (lane & 15);
        boff[kk][n] = 16384 + row * 64 + (((kk * 4 + colg) ^ (row & 7)) * 8);
      }
    }
  }

  f32x4 acc[4][4];
#pragma unroll
  for (int i = 0; i < 4; i++)
#pragma unroll
    for (int j = 0; j < 4; j++) acc[i][j] = f32x4{0.f, 0.f, 0.f, 0.f};

  auto compute = [&](const unsigned short* base) {
#pragma unroll
    for (int kk = 0; kk < 2; kk++) {
      b16x8 aF[4], bF[4];
#pragma unroll
      for (int m = 0; m < 4; m++) aF[m] = *(const b16x8*)(base + aoff[kk][m]);
#pragma unroll
      for (int n = 0; n < 4; n++) bF[n] = *(const b16x8*)(base + boff[kk][n]);
#pragma unroll
      for (int m = 0; m < 4; m++)
#pragma unroll
        for (int n = 0; n < 4; n++)
          acc[m][n] = __builtin_amdgcn_mfma_f32_16x16x32_bf16(aF[m], bF[n], acc[m][n], 0, 0, 0);
    }
  };

#pragma unroll
  for (int j = 0; j < 4; j++) gload_lds16(gsrc[j], (void*)(&lds[0][ldsoff[j]]));
  DRAIN_VMCNT();
  __syncthreads();

  int cur = 0;
  const int NK = DFF_ / 64;  // 64
  for (int kt = 0; kt < NK; kt++) {
    if (kt + 1 < NK) {
#pragma unroll
      for (int j = 0; j < 4; j++)
        gload_lds16(gsrc[j] + (kt + 1) * 64, (void*)(&lds[cur ^ 1][ldsoff[j]]));
    }
    compute(&lds[cur][0]);
    DRAIN_VMCNT();
    __syncthreads();
    cur ^= 1;
  }

#pragma unroll
  for (int n = 0; n < 4; n++) {
    int col = n0 + wc * 64 + n * 16 + (lane & 15);
    float bb3 = b3[e * DIM + col];
#pragma unroll
    for (int m = 0; m < 4; m++) {
      int rbase = wr * 64 + m * 16 + (lane >> 4) * 4;
#pragma unroll
      for (int r = 0; r < 4; r++) {
        int rr = rbase + r;
        if (m0 + rr < Me) {
          int pos = off + m0 + rr;
          float v = list_w[pos] * (acc[m][n][r] + bb3);
          atomicAdd(&y[(size_t)list_tok[pos] * DIM + col], v);
        }
      }
    }
  }
}

extern "C" void kernel_launch(void* const* d_in, const int* in_sizes, int n_in,
                              void* d_out, int out_size, void* d_ws, size_t ws_size,
                              hipStream_t stream) {
  (void)in_sizes; (void)n_in; (void)ws_size;
  const float* x  = (const float*)d_in[0];
  const float* Wr = (const float*)d_in[1];
  const float* br = (const float*)d_in[2];
  const float* W1 = (const float*)d_in[3];
  const float* b1 = (const float*)d_in[4];
  const float* W2 = (const float*)d_in[5];
  const float* b2 = (const float*)d_in[6];
  const float* W3 = (const float*)d_in[7];
  const float* b3 = (const float*)d_in[8];
  float* y = (float*)d_out;
  char* ws = (char*)d_ws;

  const size_t matB = (size_t)NE * DFF_ * DIM * 2;     // 64 MB per transposed bf16 matrix
  size_t oW1T = 0;
  size_t oW2T = oW1T + matB;
  size_t oXbf = oW2T + matB;                           // W3T reuses oW1T after gemm1
  size_t oH   = oXbf + (size_t)T_TOK * DIM * 2;
  size_t oT2e = oH + (size_t)2 * T_TOK * DFF_ * 2;
  size_t oT2w = oT2e + (size_t)2 * T_TOK * 4;
  size_t oLtk = oT2w + (size_t)2 * T_TOK * 4;
  size_t oLw  = oLtk + (size_t)2 * T_TOK * 4;
  size_t oCtl = oLw + (size_t)2 * T_TOK * 4;

  unsigned short* W1T = (unsigned short*)(ws + oW1T);
  unsigned short* W2T = (unsigned short*)(ws + oW2T);
  unsigned short* W3T = (unsigned short*)(ws + oW1T);  // reuse after gemm1
  unsigned short* Xbf = (unsigned short*)(ws + oXbf);
  unsigned short* Hb  = (unsigned short*)(ws + oH);
  int*   top2e = (int*)(ws + oT2e);
  float* top2w = (float*)(ws + oT2w);
  int*   ltok  = (int*)(ws + oLtk);
  float* lw    = (float*)(ws + oLw);
  int*   ctrl  = (int*)(ws + oCtl);

  hipMemsetAsync(y, 0, (size_t)out_size * 4, stream);
  hipMemsetAsync(ctrl, 0, (32 + 2 * MAXT) * 4, stream);

  transpose_cvt12<<<dim3(DFF_ / 64, DIM / 64, 2 * NE), 256, 0, stream>>>(W1, W2, W1T, W2T);
  router_k<<<dim3(T_TOK / 4), 256, 0, stream>>>(x, Wr, br, Xbf, top2e, top2w, ctrl);
  scan_build<<<dim3(1), 64, 0, stream>>>(ctrl);
  scatter_k<<<dim3(T_TOK / 256), 256, 0, stream>>>(top2e, top2w, ctrl + 16, ltok, lw);
  gemm1_k<<<dim3(DFF_ / 128, 71), 1024, 0, stream>>>(Xbf, W1T, W2T, b1, b2, Hb, ltok, ctrl);
  transpose_cvt<<<dim3(DIM / 64, DFF_ / 64, NE), 256, 0, stream>>>(W3, W3T, DFF_, DIM);
  gemm2_k<<<dim3(DIM / 256, 71), 1024, 0, stream>>>(Hb, W3T, b3, ltok, lw, y, ctrl);
}